// Round 1
// baseline (152.787 us; speedup 1.0000x reference)
//
#include <hip/hip_runtime.h>

// Glow coupling layer, fused single kernel.
// rows N = B*T = 262144, C=64. x1 = cols 0..31, x2 = cols 32..63.
// r2 = MLP_s2(x2); y1 = e(s2)*x1 + t2; r1 = MLP_s1(y1); y2 = e(s1)*x2 + t1.
// out = [y1 | y2], fp32.
//
// MFMA: v_mfma_f32_16x16x32_bf16.
//   A frag: lane l holds A[row = l&15][k = (l>>4)*8 + j], j=0..7
//   B frag: lane l holds B[k = (l>>4)*8 + j][col = l&15]
//   C/D  : lane l reg i -> (row = (l>>4)*4 + i, col = l&15)   [m89/m91 verified]
// Weights bf16 (plain); matmul *inputs* (x2, y1) split bf16 hi+lo (2 MFMAs on layer 1).

using bf16x8 = __attribute__((ext_vector_type(8))) short;
using f32x4  = __attribute__((ext_vector_type(4))) float;

__device__ __forceinline__ unsigned short f2bf(float f) {
    unsigned int u = __float_as_uint(f);
    u += 0x7FFFu + ((u >> 16) & 1u);        // round-to-nearest-even
    return (unsigned short)(u >> 16);
}
__device__ __forceinline__ float bf2f(unsigned short h) {
    return __uint_as_float(((unsigned int)h) << 16);
}

__device__ __forceinline__ f32x4 mfma16(bf16x8 a, bf16x8 b, f32x4 c) {
    return __builtin_amdgcn_mfma_f32_16x16x32_bf16(a, b, c, 0, 0, 0);
}

#define PITCH_A 36   // uint32 per row (packed hi/lo bf16), pad: 144B pitch, 2-way max
#define PITCH_H 136  // bf16 per row, pad: 272B pitch, 2-way max
#define PITCH_S 33   // f32 per row

// LDS offsets (bytes)
#define OFF_XT 0          // float [64][64]            = 16384
#define OFF_AP 16384      // uint  [64][36]            =  9216
#define OFF_H1 25600      // bf16  [64][136]           = 17408  (sbuf aliases this)
#define OFF_H2 43008      // bf16  [64][136]           = 17408
#define LDS_BYTES 60416

__device__ __forceinline__ bf16x8 load_wfrag(const float* __restrict__ W, int K, int frow, int k0) {
    const float4* p = reinterpret_cast<const float4*>(W + (size_t)frow * K + k0);
    float4 a = p[0], b = p[1];
    bf16x8 r;
    r[0] = (short)f2bf(a.x); r[1] = (short)f2bf(a.y);
    r[2] = (short)f2bf(a.z); r[3] = (short)f2bf(a.w);
    r[4] = (short)f2bf(b.x); r[5] = (short)f2bf(b.y);
    r[6] = (short)f2bf(b.z); r[7] = (short)f2bf(b.w);
    return r;
}

__device__ __forceinline__ void unpack_planes(const unsigned int* __restrict__ ap, int r, int lg,
                                              bf16x8& ahi, bf16x8& alo) {
    const uint4* p = reinterpret_cast<const uint4*>(ap + r * PITCH_A + lg * 8);
    uint4 q0 = p[0], q1 = p[1];
    union U { bf16x8 v; unsigned int u[4]; };
    U h, l;
    h.u[0] = (q0.x & 0xFFFFu) | (q0.y << 16);
    h.u[1] = (q0.z & 0xFFFFu) | (q0.w << 16);
    h.u[2] = (q1.x & 0xFFFFu) | (q1.y << 16);
    h.u[3] = (q1.z & 0xFFFFu) | (q1.w << 16);
    l.u[0] = (q0.x >> 16) | (q0.y & 0xFFFF0000u);
    l.u[1] = (q0.z >> 16) | (q0.w & 0xFFFF0000u);
    l.u[2] = (q1.x >> 16) | (q1.y & 0xFFFF0000u);
    l.u[3] = (q1.z >> 16) | (q1.w & 0xFFFF0000u);
    ahi = h.v; alo = l.v;
}

// One 3-layer MLP for a 64-row tile. Result (64 x 64, +bias) left in rr:
// rr[m][i] = r[16m + (lane>>4)*4 + i][16*wave + (lane&15)]
__device__ __forceinline__ void run_mlp(
    const float* __restrict__ w1, const float* __restrict__ b1,
    const float* __restrict__ w2, const float* __restrict__ b2,
    const float* __restrict__ w3, const float* __restrict__ b3,
    const unsigned int* __restrict__ ap, unsigned short* h1, unsigned short* h2,
    int wave, int lane, f32x4 (&rr)[4])
{
    const int lr = lane & 15, lg = lane >> 4;

    // -------- per-wave weight fragments (bf16) --------
    bf16x8 wb1[2], wb2[2][4], wb3[4];
    float bias1[2], bias2[2], bias3;
    #pragma unroll
    for (int f = 0; f < 2; ++f) {
        int frow = 16 * (2 * wave + f) + lr;
        wb1[f] = load_wfrag(w1, 32, frow, lg * 8);
        bias1[f] = b1[frow];
        bias2[f] = b2[frow];
        #pragma unroll
        for (int ks = 0; ks < 4; ++ks)
            wb2[f][ks] = load_wfrag(w2, 128, frow, 32 * ks + lg * 8);
    }
    {
        int frow = 16 * wave + lr;
        #pragma unroll
        for (int ks = 0; ks < 4; ++ks)
            wb3[ks] = load_wfrag(w3, 128, frow, 32 * ks + lg * 8);
        bias3 = b3[frow];
    }

    // -------- layer 1: K=32, A = hi/lo split planes --------
    #pragma unroll
    for (int m = 0; m < 4; ++m) {
        bf16x8 ahi, alo;
        unpack_planes(ap, 16 * m + lr, lg, ahi, alo);
        #pragma unroll
        for (int f = 0; f < 2; ++f) {
            f32x4 acc = {0.f, 0.f, 0.f, 0.f};
            acc = mfma16(ahi, wb1[f], acc);
            acc = mfma16(alo, wb1[f], acc);
            #pragma unroll
            for (int i = 0; i < 4; ++i) {
                float v = acc[i] + bias1[f];
                h1[(16 * m + lg * 4 + i) * PITCH_H + 16 * (2 * wave + f) + lr] =
                    (unsigned short)f2bf(fmaxf(v, 0.f));
            }
        }
    }
    __syncthreads();

    // -------- layer 2: K=128 --------
    #pragma unroll
    for (int m = 0; m < 4; ++m) {
        f32x4 acc0 = {0.f,0.f,0.f,0.f}, acc1 = {0.f,0.f,0.f,0.f};
        #pragma unroll
        for (int ks = 0; ks < 4; ++ks) {
            bf16x8 a = *reinterpret_cast<const bf16x8*>(
                h1 + (16 * m + lr) * PITCH_H + ks * 32 + lg * 8);
            acc0 = mfma16(a, wb2[0][ks], acc0);
            acc1 = mfma16(a, wb2[1][ks], acc1);
        }
        #pragma unroll
        for (int i = 0; i < 4; ++i) {
            h2[(16 * m + lg * 4 + i) * PITCH_H + 16 * (2 * wave + 0) + lr] =
                (unsigned short)f2bf(fmaxf(acc0[i] + bias2[0], 0.f));
            h2[(16 * m + lg * 4 + i) * PITCH_H + 16 * (2 * wave + 1) + lr] =
                (unsigned short)f2bf(fmaxf(acc1[i] + bias2[1], 0.f));
        }
    }
    __syncthreads();

    // -------- layer 3: K=128, F=64 (wave owns cols 16w..16w+15) --------
    #pragma unroll
    for (int m = 0; m < 4; ++m) {
        f32x4 acc = {0.f,0.f,0.f,0.f};
        #pragma unroll
        for (int ks = 0; ks < 4; ++ks) {
            bf16x8 a = *reinterpret_cast<const bf16x8*>(
                h2 + (16 * m + lr) * PITCH_H + ks * 32 + lg * 8);
            acc = mfma16(a, wb3[ks], acc);
        }
        #pragma unroll
        for (int i = 0; i < 4; ++i) acc[i] += bias3;
        rr[m] = acc;
    }
}

extern "C" __global__ void __launch_bounds__(256)
glow_kernel(const float* __restrict__ x,
            const float* __restrict__ s1w1, const float* __restrict__ s1b1,
            const float* __restrict__ s1w2, const float* __restrict__ s1b2,
            const float* __restrict__ s1w3, const float* __restrict__ s1b3,
            const float* __restrict__ s2w1, const float* __restrict__ s2b1,
            const float* __restrict__ s2w2, const float* __restrict__ s2b2,
            const float* __restrict__ s2w3, const float* __restrict__ s2b3,
            float* __restrict__ out)
{
    __shared__ __align__(16) char lds[LDS_BYTES];
    float*          xt   = reinterpret_cast<float*>(lds + OFF_XT);
    unsigned int*   ap   = reinterpret_cast<unsigned int*>(lds + OFF_AP);
    unsigned short* h1   = reinterpret_cast<unsigned short*>(lds + OFF_H1);
    unsigned short* h2   = reinterpret_cast<unsigned short*>(lds + OFF_H2);
    float*          sbuf = reinterpret_cast<float*>(lds + OFF_H1);   // alias, h1 dead when used

    const int tid  = threadIdx.x;
    const int wave = tid >> 6, lane = tid & 63;
    const int lr = lane & 15, lg = lane >> 4;
    const size_t rowbase = (size_t)blockIdx.x * 64;
    const float* xblk = x + rowbase * 64;

    // ---- Phase A: stage x tile; pack x2 hi/lo planes ----
    #pragma unroll
    for (int it = 0; it < 4; ++it) {
        int idx = (it * 256 + tid) * 4;     // float index in 64x64 tile
        float4 v = *reinterpret_cast<const float4*>(xblk + idx);
        *reinterpret_cast<float4*>(xt + idx) = v;
        int r = idx >> 6, c = idx & 63;
        if (c >= 32) {
            float vv[4] = {v.x, v.y, v.z, v.w};
            #pragma unroll
            for (int j = 0; j < 4; ++j) {
                unsigned short hi = f2bf(vv[j]);
                unsigned short lo = f2bf(vv[j] - bf2f(hi));
                ap[r * PITCH_A + (c - 32) + j] = (unsigned int)hi | ((unsigned int)lo << 16);
            }
        }
    }
    __syncthreads();

    f32x4 rr[4];

    // ---- MLP on x2 with s2 weights ----
    run_mlp(s2w1, s2b1, s2w2, s2b2, s2w3, s2b3, ap, h1, h2, wave, lane, rr);

    // waves 0,1 hold s2 (cols 0..31) -> stash to sbuf (aliases h1; h1 dead)
    if (wave < 2) {
        #pragma unroll
        for (int m = 0; m < 4; ++m)
            #pragma unroll
            for (int i = 0; i < 4; ++i)
                sbuf[(16 * m + lg * 4 + i) * PITCH_S + 16 * wave + lr] = rr[m][i];
    }
    __syncthreads();

    // waves 2,3 hold t2 (cols 32..63): y1 = e(s2)*x1 + t2 -> out + split planes
    if (wave >= 2) {
        const int c = 16 * (wave - 2) + lr;   // 0..31
        #pragma unroll
        for (int m = 0; m < 4; ++m) {
            #pragma unroll
            for (int i = 0; i < 4; ++i) {
                int r = 16 * m + lg * 4 + i;
                float s = sbuf[r * PITCH_S + c];
                float e = __expf(3.18f * atanf(s * 0.2f));
                float y = e * xt[r * 64 + c] + rr[m][i];
                out[(rowbase + r) * 64 + c] = y;
                unsigned short hi = f2bf(y);
                unsigned short lo = f2bf(y - bf2f(hi));
                ap[r * PITCH_A + c] = (unsigned int)hi | ((unsigned int)lo << 16);
            }
        }
    }
    __syncthreads();

    // ---- MLP on y1 with s1 weights ----
    run_mlp(s1w1, s1b1, s1w2, s1b2, s1w3, s1b3, ap, h1, h2, wave, lane, rr);

    if (wave < 2) {
        #pragma unroll
        for (int m = 0; m < 4; ++m)
            #pragma unroll
            for (int i = 0; i < 4; ++i)
                sbuf[(16 * m + lg * 4 + i) * PITCH_S + 16 * wave + lr] = rr[m][i];
    }
    __syncthreads();

    // y2 = e(s1)*x2 + t1 -> out cols 32..63
    if (wave >= 2) {
        const int c = 16 * (wave - 2) + lr;   // 0..31
        #pragma unroll
        for (int m = 0; m < 4; ++m) {
            #pragma unroll
            for (int i = 0; i < 4; ++i) {
                int r = 16 * m + lg * 4 + i;
                float s = sbuf[r * PITCH_S + c];
                float e = __expf(3.18f * atanf(s * 0.2f));
                float y = e * xt[r * 64 + 32 + c] + rr[m][i];
                out[(rowbase + r) * 64 + 32 + c] = y;
            }
        }
    }
}

extern "C" void kernel_launch(void* const* d_in, const int* in_sizes, int n_in,
                              void* d_out, int out_size, void* d_ws, size_t ws_size,
                              hipStream_t stream) {
    const float* x    = (const float*)d_in[0];
    const float* s1w1 = (const float*)d_in[1];
    const float* s1b1 = (const float*)d_in[2];
    const float* s1w2 = (const float*)d_in[3];
    const float* s1b2 = (const float*)d_in[4];
    const float* s1w3 = (const float*)d_in[5];
    const float* s1b3 = (const float*)d_in[6];
    const float* s2w1 = (const float*)d_in[7];
    const float* s2b1 = (const float*)d_in[8];
    const float* s2w2 = (const float*)d_in[9];
    const float* s2b2 = (const float*)d_in[10];
    const float* s2w3 = (const float*)d_in[11];
    const float* s2b3 = (const float*)d_in[12];
    float* out = (float*)d_out;

    int nrows   = in_sizes[0] / 64;   // 262144
    int nblocks = nrows / 64;         // 4096

    hipLaunchKernelGGL(glow_kernel, dim3(nblocks), dim3(256), 0, stream,
                       x, s1w1, s1b1, s1w2, s1b2, s1w3, s1b3,
                       s2w1, s2b1, s2w2, s2b2, s2w3, s2b3, out);
}

// Round 2
// 78.966 us; speedup vs baseline: 1.9348x; 1.9348x over previous
//
#include <hip/hip_runtime.h>

// Glow coupling layer, fused. rows N = 262144, C = 64.
// r2 = MLP_s2(x2); y1 = e(s2)*x1 + t2; r1 = MLP_s1(y1); y2 = e(s1)*x2 + t1.
//
// Round 2: weight prep kernel (bf16 MFMA fragments in d_ws), LDS 52.3KB
// (3 blocks/CU), balanced exp epilogue, plane arrays (no bit-unpack).
//
// MFMA v_mfma_f32_16x16x32_bf16 layouts (m89/m91 verified):
//   A frag: lane l holds A[row=l&15][k=(l>>4)*8+j]
//   B frag: lane l holds B[k=(l>>4)*8+j][col=l&15]
//   C/D  : lane l reg i -> (row=(l>>4)*4+i, col=l&15)

using bf16x8 = __attribute__((ext_vector_type(8))) short;
using f32x4  = __attribute__((ext_vector_type(4))) float;
using s16x4  = __attribute__((ext_vector_type(4))) short;

__device__ __forceinline__ unsigned short f2bf(float f) {
    unsigned int u = __float_as_uint(f);
    u += 0x7FFFu + ((u >> 16) & 1u);
    return (unsigned short)(u >> 16);
}
__device__ __forceinline__ float bf2f(unsigned short h) {
    return __uint_as_float(((unsigned int)h) << 16);
}
__device__ __forceinline__ f32x4 mfma16(bf16x8 a, bf16x8 b, f32x4 c) {
    return __builtin_amdgcn_mfma_f32_16x16x32_bf16(a, b, c, 0, 0, 0);
}

#define X1P 33    // f32 pitch
#define APP 40    // bf16 pitch (plane arrays), 80B rows -> 16B-aligned frag reads
#define HP  136   // bf16 pitch for h buffers (272B rows)

#define OFF_X1   0        // f32  [64][33]  = 8448
#define OFF_AHI2 8448     // bf16 [64][40]  = 5120
#define OFF_ALO2 13568    // bf16 [64][40]  = 5120
#define OFF_H1   18688    // bf16 [64][136] = 17408  (sbuf f32[64][33] aliases)
#define OFF_H2   36096    // bf16 [64][136] = 17408  (y1 planes alias: ahi1/alo1)
#define LDS_BYTES 53504

#define BIAS_OFF 114688           // 112 tiles * 1024B
#define WS_NEED  (114688 + 2560)  // + 2 mlp * 320 f32 biases

struct MlpW {
    bf16x8 wb1[2];
    bf16x8 wb2[2][4];
    bf16x8 wb3[4];
    float  b1v[2], b2v[2], b3v;
};

// ---- fallback: convert weights per block (MODE 0) ----
__device__ __forceinline__ bf16x8 load_wfrag(const float* __restrict__ W, int K, int frow, int k0) {
    const float4* p = reinterpret_cast<const float4*>(W + (size_t)frow * K + k0);
    float4 a = p[0], b = p[1];
    bf16x8 r;
    r[0] = (short)f2bf(a.x); r[1] = (short)f2bf(a.y);
    r[2] = (short)f2bf(a.z); r[3] = (short)f2bf(a.w);
    r[4] = (short)f2bf(b.x); r[5] = (short)f2bf(b.y);
    r[6] = (short)f2bf(b.z); r[7] = (short)f2bf(b.w);
    return r;
}

__device__ __forceinline__ void load_w_convert(
    const float* __restrict__ w1, const float* __restrict__ b1,
    const float* __restrict__ w2, const float* __restrict__ b2,
    const float* __restrict__ w3, const float* __restrict__ b3,
    int wave, int lane, MlpW& W)
{
    const int lr = lane & 15, lg = lane >> 4;
    #pragma unroll
    for (int f = 0; f < 2; ++f) {
        int frow = 16 * (2 * wave + f) + lr;
        W.wb1[f] = load_wfrag(w1, 32, frow, lg * 8);
        W.b1v[f] = b1[frow];
        W.b2v[f] = b2[frow];
        #pragma unroll
        for (int ks = 0; ks < 4; ++ks)
            W.wb2[f][ks] = load_wfrag(w2, 128, frow, 32 * ks + lg * 8);
    }
    int frow3 = 16 * wave + lr;
    #pragma unroll
    for (int ks = 0; ks < 4; ++ks)
        W.wb3[ks] = load_wfrag(w3, 128, frow3, 32 * ks + lg * 8);
    W.b3v = b3[frow3];
}

// ---- prepped: straight uint4 loads from d_ws (MODE 1) ----
__device__ __forceinline__ void load_w_prepped(const char* __restrict__ wsb,
                                               int mlp, int wave, int lane, MlpW& W)
{
    const int lr = lane & 15;
    const uint4* base = reinterpret_cast<const uint4*>(wsb);
    union U { uint4 q; bf16x8 v; };
    #pragma unroll
    for (int f = 0; f < 2; ++f) {
        U u; u.q = base[(mlp * 56 + 2 * wave + f) * 64 + lane];
        W.wb1[f] = u.v;
        #pragma unroll
        for (int ks = 0; ks < 4; ++ks) {
            U u2; u2.q = base[(mlp * 56 + 8 + (2 * wave + f) * 4 + ks) * 64 + lane];
            W.wb2[f][ks] = u2.v;
        }
    }
    #pragma unroll
    for (int ks = 0; ks < 4; ++ks) {
        U u3; u3.q = base[(mlp * 56 + 40 + wave * 4 + ks) * 64 + lane];
        W.wb3[ks] = u3.v;
    }
    const float* bias = reinterpret_cast<const float*>(wsb + BIAS_OFF) + mlp * 320;
    #pragma unroll
    for (int f = 0; f < 2; ++f) {
        W.b1v[f] = bias[16 * (2 * wave + f) + lr];
        W.b2v[f] = bias[128 + 16 * (2 * wave + f) + lr];
    }
    W.b3v = bias[256 + 16 * wave + lr];
}

// ---- one 3-layer MLP over the 64-row tile ----
// input from plane arrays (ahi+alo, exact fp32 split); result in rr:
// rr[m][i] = r[16m + (lane>>4)*4 + i][16*wave + (lane&15)]
__device__ __forceinline__ void run_mlp(const MlpW& W,
    const unsigned short* __restrict__ ahi, const unsigned short* __restrict__ alo,
    unsigned short* __restrict__ h1, unsigned short* __restrict__ h2,
    int wave, int lane, f32x4 (&rr)[4])
{
    const int lr = lane & 15, lg = lane >> 4;

    // layer 1: K=32, two MFMAs (hi+lo planes)
    #pragma unroll
    for (int m = 0; m < 4; ++m) {
        int r = 16 * m + lr;
        bf16x8 ah = *reinterpret_cast<const bf16x8*>(ahi + r * APP + lg * 8);
        bf16x8 al = *reinterpret_cast<const bf16x8*>(alo + r * APP + lg * 8);
        #pragma unroll
        for (int f = 0; f < 2; ++f) {
            f32x4 acc = {0.f, 0.f, 0.f, 0.f};
            acc = mfma16(ah, W.wb1[f], acc);
            acc = mfma16(al, W.wb1[f], acc);
            #pragma unroll
            for (int i = 0; i < 4; ++i) {
                float v = acc[i] + W.b1v[f];
                h1[(16 * m + lg * 4 + i) * HP + 16 * (2 * wave + f) + lr] =
                    (unsigned short)f2bf(fmaxf(v, 0.f));
            }
        }
    }
    __syncthreads();

    // layer 2: K=128
    #pragma unroll
    for (int m = 0; m < 4; ++m) {
        f32x4 acc0 = {0.f,0.f,0.f,0.f}, acc1 = {0.f,0.f,0.f,0.f};
        #pragma unroll
        for (int ks = 0; ks < 4; ++ks) {
            bf16x8 a = *reinterpret_cast<const bf16x8*>(
                h1 + (16 * m + lr) * HP + ks * 32 + lg * 8);
            acc0 = mfma16(a, W.wb2[0][ks], acc0);
            acc1 = mfma16(a, W.wb2[1][ks], acc1);
        }
        #pragma unroll
        for (int i = 0; i < 4; ++i) {
            h2[(16 * m + lg * 4 + i) * HP + 16 * (2 * wave + 0) + lr] =
                (unsigned short)f2bf(fmaxf(acc0[i] + W.b2v[0], 0.f));
            h2[(16 * m + lg * 4 + i) * HP + 16 * (2 * wave + 1) + lr] =
                (unsigned short)f2bf(fmaxf(acc1[i] + W.b2v[1], 0.f));
        }
    }
    __syncthreads();

    // layer 3: K=128, wave owns output cols 16w..16w+15
    #pragma unroll
    for (int m = 0; m < 4; ++m) {
        f32x4 acc = {0.f,0.f,0.f,0.f};
        #pragma unroll
        for (int ks = 0; ks < 4; ++ks) {
            bf16x8 a = *reinterpret_cast<const bf16x8*>(
                h2 + (16 * m + lr) * HP + ks * 32 + lg * 8);
            acc = mfma16(a, W.wb3[ks], acc);
        }
        #pragma unroll
        for (int i = 0; i < 4; ++i) acc[i] += W.b3v;
        rr[m] = acc;
    }
}

// ---- weight prep: 112 fragment tiles (1KB each) + biases into d_ws ----
extern "C" __global__ void __launch_bounds__(256)
glow_prep(const float* __restrict__ s2w1, const float* __restrict__ s2w2,
          const float* __restrict__ s2w3, const float* __restrict__ s1w1,
          const float* __restrict__ s1w2, const float* __restrict__ s1w3,
          const float* __restrict__ s2b1, const float* __restrict__ s2b2,
          const float* __restrict__ s2b3, const float* __restrict__ s1b1,
          const float* __restrict__ s1b2, const float* __restrict__ s1b3,
          char* __restrict__ wsb)
{
    const int wave = threadIdx.x >> 6, lane = threadIdx.x & 63;
    const int lr = lane & 15, lg = lane >> 4;
    const int gw = blockIdx.x * 4 + wave;

    if (gw < 112) {
        int mlp = gw / 56, t = gw % 56;
        const float* Ws[2][3] = {{s2w1, s2w2, s2w3}, {s1w1, s1w2, s1w3}};
        const float* W; int K, row, k0;
        if (t < 8)       { W = Ws[mlp][0]; K = 32;  row = 16 * t + lr;          k0 = lg * 8; }
        else if (t < 40) { int u = t - 8;  W = Ws[mlp][1]; K = 128; row = 16 * (u >> 2) + lr; k0 = 32 * (u & 3) + lg * 8; }
        else             { int u = t - 40; W = Ws[mlp][2]; K = 128; row = 16 * (u >> 2) + lr; k0 = 32 * (u & 3) + lg * 8; }
        const float* p = W + (size_t)row * K + k0;
        union U { uint4 q; bf16x8 v; } u;
        #pragma unroll
        for (int j = 0; j < 8; ++j) u.v[j] = (short)f2bf(p[j]);
        reinterpret_cast<uint4*>(wsb)[gw * 64 + lane] = u.q;
    } else if (blockIdx.x == 28) {
        const float* Bs[6] = {s2b1, s2b2, s2b3, s1b1, s1b2, s1b3};
        const int sz[6] = {128, 128, 64, 128, 128, 64};
        float* dst = reinterpret_cast<float*>(wsb + BIAS_OFF);
        for (int i = threadIdx.x; i < 640; i += 256) {
            int j = i, a = 0;
            while (j >= sz[a]) { j -= sz[a]; ++a; }
            dst[i] = Bs[a][j];
        }
    }
}

template<int MODE>
__global__ void __launch_bounds__(256)
glow_main(const float* __restrict__ x,
          const float* __restrict__ s1w1, const float* __restrict__ s1b1,
          const float* __restrict__ s1w2, const float* __restrict__ s1b2,
          const float* __restrict__ s1w3, const float* __restrict__ s1b3,
          const float* __restrict__ s2w1, const float* __restrict__ s2b1,
          const float* __restrict__ s2w2, const float* __restrict__ s2b2,
          const float* __restrict__ s2w3, const float* __restrict__ s2b3,
          const char* __restrict__ wsb, float* __restrict__ out)
{
    __shared__ __align__(16) char lds[LDS_BYTES];
    float*          x1   = reinterpret_cast<float*>(lds + OFF_X1);
    unsigned short* ahi2 = reinterpret_cast<unsigned short*>(lds + OFF_AHI2);
    unsigned short* alo2 = reinterpret_cast<unsigned short*>(lds + OFF_ALO2);
    unsigned short* h1   = reinterpret_cast<unsigned short*>(lds + OFF_H1);
    unsigned short* h2   = reinterpret_cast<unsigned short*>(lds + OFF_H2);
    float*          sbuf = reinterpret_cast<float*>(lds + OFF_H1);          // alias h1
    unsigned short* ahi1 = reinterpret_cast<unsigned short*>(lds + OFF_H2); // alias h2
    unsigned short* alo1 = reinterpret_cast<unsigned short*>(lds + OFF_H2 + 5120);

    const int tid  = threadIdx.x;
    const int wave = tid >> 6, lane = tid & 63;
    const int lr = lane & 15, lg = lane >> 4;
    const size_t rowbase = (size_t)blockIdx.x * 64;
    const float* xblk = x + rowbase * 64;

    // ---- Phase A: stage x1 (f32) and x2 (hi/lo bf16 planes) ----
    #pragma unroll
    for (int it = 0; it < 4; ++it) {
        int idx = (it * 256 + tid) * 4;
        int r = idx >> 6, c = idx & 63;
        float4 v = *reinterpret_cast<const float4*>(xblk + idx);
        if (c < 32) {
            x1[r * X1P + c + 0] = v.x;
            x1[r * X1P + c + 1] = v.y;
            x1[r * X1P + c + 2] = v.z;
            x1[r * X1P + c + 3] = v.w;
        } else {
            int cc = c - 32;
            float vv[4] = {v.x, v.y, v.z, v.w};
            s16x4 hi, lo;
            #pragma unroll
            for (int j = 0; j < 4; ++j) {
                unsigned short h = f2bf(vv[j]);
                hi[j] = (short)h;
                lo[j] = (short)f2bf(vv[j] - bf2f(h));
            }
            *reinterpret_cast<s16x4*>(ahi2 + r * APP + cc) = hi;
            *reinterpret_cast<s16x4*>(alo2 + r * APP + cc) = lo;
        }
    }

    MlpW W;
    if (MODE) load_w_prepped(wsb, 0, wave, lane, W);
    else      load_w_convert(s2w1, s2b1, s2w2, s2b2, s2w3, s2b3, wave, lane, W);
    __syncthreads();

    f32x4 rr[4];

    // ---- MLP s2 on x2 ----
    run_mlp(W, ahi2, alo2, h1, h2, wave, lane, rr);

    // epilogue 1: stash s2 -> balanced e() -> y1 = e*x1 + t2
    if (wave < 2) {
        #pragma unroll
        for (int m = 0; m < 4; ++m)
            #pragma unroll
            for (int i = 0; i < 4; ++i)
                sbuf[(16 * m + lg * 4 + i) * X1P + 16 * wave + lr] = rr[m][i];
    }
    __syncthreads();
    {   // all 256 threads: e = exp(3.18*atan(s/5)) on 8 elements each
        int r = tid >> 2, c0 = (tid & 3) * 8;
        #pragma unroll
        for (int j = 0; j < 8; ++j) {
            float s = sbuf[r * X1P + c0 + j];
            sbuf[r * X1P + c0 + j] = __expf(3.18f * atanf(s * 0.2f));
        }
    }
    __syncthreads();
    if (wave >= 2) {
        const int c = 16 * (wave - 2) + lr;
        #pragma unroll
        for (int m = 0; m < 4; ++m) {
            #pragma unroll
            for (int i = 0; i < 4; ++i) {
                int r = 16 * m + lg * 4 + i;
                float y = fmaf(sbuf[r * X1P + c], x1[r * X1P + c], rr[m][i]);
                out[(rowbase + r) * 64 + c] = y;
                unsigned short h = f2bf(y);
                ahi1[r * APP + c] = h;
                alo1[r * APP + c] = f2bf(y - bf2f(h));
            }
        }
    }
    if (MODE) load_w_prepped(wsb, 1, wave, lane, W);
    else      load_w_convert(s1w1, s1b1, s1w2, s1b2, s1w3, s1b3, wave, lane, W);
    __syncthreads();

    // ---- MLP s1 on y1 ----
    run_mlp(W, ahi1, alo1, h1, h2, wave, lane, rr);

    // epilogue 2: stash s1 -> balanced e() -> y2 = e*x2 + t1
    if (wave < 2) {
        #pragma unroll
        for (int m = 0; m < 4; ++m)
            #pragma unroll
            for (int i = 0; i < 4; ++i)
                sbuf[(16 * m + lg * 4 + i) * X1P + 16 * wave + lr] = rr[m][i];
    }
    __syncthreads();
    {
        int r = tid >> 2, c0 = (tid & 3) * 8;
        #pragma unroll
        for (int j = 0; j < 8; ++j) {
            float s = sbuf[r * X1P + c0 + j];
            sbuf[r * X1P + c0 + j] = __expf(3.18f * atanf(s * 0.2f));
        }
    }
    __syncthreads();
    if (wave >= 2) {
        const int c = 16 * (wave - 2) + lr;
        #pragma unroll
        for (int m = 0; m < 4; ++m) {
            #pragma unroll
            for (int i = 0; i < 4; ++i) {
                int r = 16 * m + lg * 4 + i;
                float x2v = bf2f((unsigned short)ahi2[r * APP + c]) +
                            bf2f((unsigned short)alo2[r * APP + c]);
                float y = fmaf(sbuf[r * X1P + c], x2v, rr[m][i]);
                out[(rowbase + r) * 64 + 32 + c] = y;
            }
        }
    }
}

extern "C" void kernel_launch(void* const* d_in, const int* in_sizes, int n_in,
                              void* d_out, int out_size, void* d_ws, size_t ws_size,
                              hipStream_t stream) {
    const float* x    = (const float*)d_in[0];
    const float* s1w1 = (const float*)d_in[1];
    const float* s1b1 = (const float*)d_in[2];
    const float* s1w2 = (const float*)d_in[3];
    const float* s1b2 = (const float*)d_in[4];
    const float* s1w3 = (const float*)d_in[5];
    const float* s1b3 = (const float*)d_in[6];
    const float* s2w1 = (const float*)d_in[7];
    const float* s2b1 = (const float*)d_in[8];
    const float* s2w2 = (const float*)d_in[9];
    const float* s2b2 = (const float*)d_in[10];
    const float* s2w3 = (const float*)d_in[11];
    const float* s2b3 = (const float*)d_in[12];
    float* out = (float*)d_out;
    char* wsb  = (char*)d_ws;

    int nrows   = in_sizes[0] / 64;   // 262144
    int nblocks = nrows / 64;         // 4096

    if (ws_size >= (size_t)WS_NEED) {
        hipLaunchKernelGGL(glow_prep, dim3(29), dim3(256), 0, stream,
                           s2w1, s2w2, s2w3, s1w1, s1w2, s1w3,
                           s2b1, s2b2, s2b3, s1b1, s1b2, s1b3, wsb);
        hipLaunchKernelGGL((glow_main<1>), dim3(nblocks), dim3(256), 0, stream,
                           x, s1w1, s1b1, s1w2, s1b2, s1w3, s1b3,
                           s2w1, s2b1, s2w2, s2b2, s2w3, s2b3, wsb, out);
    } else {
        hipLaunchKernelGGL((glow_main<0>), dim3(nblocks), dim3(256), 0, stream,
                           x, s1w1, s1b1, s1w2, s1b2, s1w3, s1b3,
                           s2w1, s2b1, s2w2, s2b2, s2w3, s2b3, wsb, out);
    }
}